// Round 11
// baseline (141.606 us; speedup 1.0000x reference)
//
#include <hip/hip_runtime.h>
#include <stdint.h>

typedef _Float16 f16;
typedef f16  f16x8 __attribute__((ext_vector_type(8)));
typedef f16  f16x4 __attribute__((ext_vector_type(4)));
typedef f16  f16x2 __attribute__((ext_vector_type(2)));
typedef float f32x4 __attribute__((ext_vector_type(4)));

#define W 512
#define H 512
#define KS 11
#define NW 4                // waves per block
#define NBLK 6144           // 48 slices * 8 tx * 16 ty32 (64x32 out per block)
#define NLINES 256          // spread accumulator lines (64 B apart)
#define C1_SSIM 0.0001f
#define C2_SSIM 0.0009f
#define NTOTAL 12582912.0f

// Window per tile: 80 cols x 48 rows f32 per image (320 B row stride).
// 48*320 = 15360 B = 15 x 1-KB DMA chunks per image; 2 images = 30 KB LDS
// -> 5 blocks/CU (launch_bounds(256,5)) = 20 waves/CU = 5 waves/SIMD.
#define LCOLS 80
#define IMGF32 3840         // 48*80 f32 per image
#define NCHUNK 30

// Normalized separable Gaussian (ksize=11, sigma=1.5), f32 master copy.
__device__ __constant__ const float GW[KS] = {
    1.02838e-3f, 7.59876e-3f, 3.600076e-2f, 1.0936069e-1f, 2.1300554e-1f,
    2.6601172e-1f,
    2.1300554e-1f, 1.0936069e-1f, 3.600076e-2f, 7.59876e-3f, 1.02838e-3f
};

__device__ inline float ssim_px(float ux, float uy, float uxx, float uyy, float uxy) {
    const float uxuy = ux * uy;
    const float a = 2.f * uxuy + C1_SSIM;
    const float b = 2.f * (uxy - uxuy) + C2_SSIM;
    const float c = ux * ux + uy * uy + C1_SSIM;
    const float d = (uxx - ux * ux) + (uyy - uy * uy) + C2_SSIM;
    return (a * b) * __builtin_amdgcn_rcpf(c * d);
}

__device__ __forceinline__ f16x8 pack84(f32x4 a, f32x4 b) {
    f16x8 r;
    f16x2 h;
    h = __builtin_bit_cast(f16x2, __builtin_amdgcn_cvt_pkrtz(a[0], a[1]));
    r[0] = h[0]; r[1] = h[1];
    h = __builtin_bit_cast(f16x2, __builtin_amdgcn_cvt_pkrtz(a[2], a[3]));
    r[2] = h[0]; r[3] = h[1];
    h = __builtin_bit_cast(f16x2, __builtin_amdgcn_cvt_pkrtz(b[0], b[1]));
    r[4] = h[0]; r[5] = h[1];
    h = __builtin_bit_cast(f16x2, __builtin_amdgcn_cvt_pkrtz(b[2], b[3]));
    r[6] = h[0]; r[7] = h[1];
    return r;
}

// Combines the two individually-proven mechanisms, first time together:
//  - DMA staging (global_load_lds, R5/R10): staging touches NO registers,
//    so the compiler cannot serialize it (fatal flaw of reg-staged R1-R4)
//    and the burst costs ~issue + one latency.
//  - High occupancy (R4): 5 blocks/CU = 5 waves/SIMD in the COMPUTE phase.
//    R10 isolated the ~46-us plateau to dependency stalls at 2 waves/SIMD
//    (9000 cy/iter vs ~3000 busy); 5 blocks also stagger their staging
//    bursts to keep HBM demand continuous statistically.
// Tile order is ty-fastest with a bijective XCD swizzle (6144%8==0), so
// vertically adjacent tiles (10 shared halo rows) hit the same XCD's L2.
// Compute = verified fragment algebra (R4/R5/R10, absmax 0.0): hconv
// D=mfma_16x16x32(img, af), -8-col window absorbed in band (d=k-n-3);
// vconv = two chained K=16 MFMAs on lane-local packed hconv rows.
__global__ __launch_bounds__(256, 5)
void ssim_main(const float* __restrict__ simg, const float* __restrict__ timg,
               float* __restrict__ accum, const float* __restrict__ zbuf) {
    __shared__ __align__(16) float lds[2 * IMGF32];
    __shared__ float red[NW];

    const int tid  = threadIdx.x;
    const int w    = tid >> 6;
    const int lane = tid & 63;
    const int n    = lane & 15;
    const int q    = lane >> 4;

    // Bijective XCD swizzle: consecutive L on one XCD; L = z*128+tx*16+ty.
    const int bid = blockIdx.x;
    const int L   = (bid & 7) * (NBLK / 8) + (bid >> 3);
    const int z   = L >> 7;               // 48 slices (16 batch * 3 ch)
    const int rr  = L & 127;
    const int tx  = rr >> 4;
    const int ty  = rr & 15;              // 32-row band

    const float* sp = simg + ((size_t)z << 18);
    const float* tp = timg + ((size_t)z << 18);
    const int ybase = (ty << 5) - 5;      // stored row 0 (48 rows)
    const int xbase = (tx << 6) - 8;      // stored col 0 (80 cols, aligned)

    // ---- PHASE 1: DMA staging, 30 x 1-KB chunks ----
    // chunk c: img=c>=15, cc=c%15; per-lane 16 B at off=cc*1024+lane*16;
    // row=off/320 (via t16=off/64<240: row=(t16*205)>>10), colb=off%320.
    // OOB lanes redirect the GLOBAL source to a zeroed line (LDS dest
    // stays wave-uniform-linear).  Wave w owns chunks c=4k+w (8/8/7/7).
    #pragma unroll
    for (int k = 0; k < 8; ++k) {
        const int c = (k << 2) + w;
        if (c < NCHUNK) {                 // wave-uniform
            const int img = (c >= 15) ? 1 : 0;
            const int cc  = img ? (c - 15) : c;
            const int off = (cc << 10) + (lane << 4);
            const int t16 = off >> 6;                 // < 240
            const int row = (t16 * 205) >> 10;        // off/320
            const int colb = off - row * 320;
            const int ry   = ybase + row;
            const int gcol = xbase + (colb >> 2);
            const float* src = img ? tp : sp;
            const bool ok = ((unsigned)ry < (unsigned)H) &
                            ((unsigned)gcol <= (unsigned)(W - 4));
            const float* ga = ok ? (src + ((size_t)ry << 9) + gcol) : zbuf;
            void* ldst = (char*)lds + img * (IMGF32 * 4) + (cc << 10);
            __builtin_amdgcn_global_load_lds(
                (const uint32_t __attribute__((address_space(1)))*)ga,
                (uint32_t __attribute__((address_space(3)))*)ldst,
                16, 0, 0);
        }
    }

    // Fragment setup under the in-flight DMA (verified algebra).
    f16x8 af;
    #pragma unroll
    for (int j = 0; j < 8; ++j) {
        const int k = (q << 3) + j;
        const int d = k - n - 3;
        af[j] = (d >= 0 && d < KS) ? (f16)GW[d] : (f16)0.f;
    }
    f16x4 a1v, a2v;
    #pragma unroll
    for (int j = 0; j < 4; ++j) {
        const int k  = (q << 2) + j;
        const int d1 = k - n;
        const int d2 = k + 16 - n;
        a1v[j] = (d1 >= 0 && d1 < KS) ? (f16)GW[d1] : (f16)0.f;
        a2v[j] = (d2 >= 0 && d2 < KS) ? (f16)GW[d2] : (f16)0.f;
    }

    __syncthreads();   // bulk drain (vmcnt 0): whole window staged

    // ---- PHASE 2: compute from LDS (3 hconv groups -> 2 vconv tiles) ----
    union H4 { f16x4 v4; f16x2 v2[2]; };
    const int coff = (w << 4) + (q << 3);   // f32 col offset: 16w + 8q
    const float* ls = lds + coff;
    const float* lt = lds + IMGF32 + coff;

    f16x4 ph[2][5];
    float sum = 0.f;

    #pragma unroll
    for (int g = 0; g < 3; ++g) {
        const int ro = ((g << 4) + n) * LCOLS;
        const f32x4 s0 = *(const f32x4*)(ls + ro);
        const f32x4 s1 = *(const f32x4*)(ls + ro + 4);
        const f32x4 t0 = *(const f32x4*)(lt + ro);
        const f32x4 t1 = *(const f32x4*)(lt + ro + 4);
        const f16x8 sf = pack84(s0, s1);
        const f16x8 tf = pack84(t0, t1);
        const int pb = g & 1;
        #pragma unroll
        for (int c = 0; c < 5; ++c) {
            f16x8 ch;
            if      (c == 0) ch = sf;
            else if (c == 1) ch = tf;
            else if (c == 2) ch = sf * sf;
            else if (c == 3) ch = tf * tf;
            else             ch = sf * tf;
            const f32x4 zero = {0.f, 0.f, 0.f, 0.f};
            const f32x4 d = __builtin_amdgcn_mfma_f32_16x16x32_f16(ch, af, zero, 0, 0, 0);
            H4 u;
            u.v2[0] = __builtin_bit_cast(f16x2, __builtin_amdgcn_cvt_pkrtz(d[0], d[1]));
            u.v2[1] = __builtin_bit_cast(f16x2, __builtin_amdgcn_cvt_pkrtz(d[2], d[3]));
            ph[pb][c] = u.v4;              // lane-local: rows 4q..4q+3 at one col
        }
        if (g >= 1) {
            const int pa = pb ^ 1;        // vconv tile t = g-1 (out rows 16t..)
            f32x4 acc[5];
            #pragma unroll
            for (int c = 0; c < 5; ++c) {
                const f32x4 zero = {0.f, 0.f, 0.f, 0.f};
                f32x4 a = __builtin_amdgcn_mfma_f32_16x16x16f16(a2v, ph[pb][c], zero, 0, 0, 0);
                a = __builtin_amdgcn_mfma_f32_16x16x16f16(a1v, ph[pa][c], a, 0, 0, 0);
                acc[c] = a;
            }
            #pragma unroll
            for (int rg = 0; rg < 4; ++rg)
                sum += ssim_px(acc[0][rg], acc[1][rg], acc[2][rg],
                               acc[3][rg], acc[4][rg]);
        }
    }

    // ---- Wave reduce, block reduce, one spread atomic per block ----
    #pragma unroll
    for (int off = 32; off > 0; off >>= 1)
        sum += __shfl_down(sum, off, 64);
    if (lane == 0) red[w] = sum;
    __syncthreads();
    if (tid == 0) {
        atomicAdd(&accum[(bid & (NLINES - 1)) << 4],
                  red[0] + red[1] + red[2] + red[3]);
    }
}

__global__ void ssim_final(const float* __restrict__ accum, float* __restrict__ out) {
    const int lane = threadIdx.x;
    float s = 0.f;
    #pragma unroll
    for (int i = 0; i < NLINES / 64; ++i)
        s += accum[((i << 6) + lane) << 4];
    #pragma unroll
    for (int off = 32; off > 0; off >>= 1)
        s += __shfl_down(s, off, 64);
    if (lane == 0) out[0] = 1.f - s * (1.f / NTOTAL);
}

extern "C" void kernel_launch(void* const* d_in, const int* in_sizes, int n_in,
                              void* d_out, int out_size, void* d_ws, size_t ws_size,
                              hipStream_t stream) {
    const float* s = (const float*)d_in[0];
    const float* t = (const float*)d_in[1];
    float* out   = (float*)d_out;
    float* accum = (float*)d_ws;                 // NLINES*16 floats = 16 KB
    const float* zbuf = accum + NLINES * 16;     // zeroed line for OOB DMA

    hipMemsetAsync(accum, 0, NLINES * 16 * sizeof(float) + 256, stream);
    ssim_main<<<dim3(NBLK), 256, 0, stream>>>(s, t, accum, zbuf);
    ssim_final<<<1, 64, 0, stream>>>(accum, out);
}